// Round 1
// baseline (1767.304 us; speedup 1.0000x reference)
//
#include <hip/hip_runtime.h>

typedef __bf16 bf16;
typedef __attribute__((ext_vector_type(8))) __bf16 bf16x8;
typedef __attribute__((ext_vector_type(4))) __bf16 bf16x4;
typedef __attribute__((ext_vector_type(4))) float f32x4;

#define GL16(gp, lp) __builtin_amdgcn_global_load_lds( \
    (const __attribute__((address_space(1))) unsigned int*)(gp), \
    (__attribute__((address_space(3))) unsigned int*)(lp), 16, 0, 0)

__device__ __forceinline__ f32x4 mfma16(bf16x8 a, bf16x8 b, f32x4 c) {
  return __builtin_amdgcn_mfma_f32_16x16x32_bf16(a, b, c, 0, 0, 0);
}

// ---------------------------------------------------------------------------
// Generic bf16 GEMM: C[M][N] = A[M][K] (bf16, row-major) * Bt[N][K]^T (bf16)
// 128x128 tile, BK=32, 4 waves (2x2 of 64x64), global_load_lds staging.
// Optional bias (fp32 [N]), residual (fp32 [M][N]), ReLU; out fp32 or bf16.
// ---------------------------------------------------------------------------
template<int RELU, int BIAS, int RES, int OUTB>
__global__ __launch_bounds__(256, 2) void gemm_k(
    const bf16* __restrict__ A, const bf16* __restrict__ Bt,
    float* __restrict__ Cf, bf16* __restrict__ Cb,
    const float* __restrict__ bias, const float* __restrict__ resid,
    int M, int N, int K)
{
  __shared__ __align__(16) bf16 Al[128 * 32];
  __shared__ __align__(16) bf16 Bl[128 * 32];
  const int tid = threadIdx.x;
  const int wid = tid >> 6, lane = tid & 63;
  const int g = lane >> 4, l16 = lane & 15;
  const int bm = blockIdx.y * 128, bn = blockIdx.x * 128;
  const int wm = (wid >> 1) * 64, wn = (wid & 1) * 64;

  const f32x4 z4 = {0.f, 0.f, 0.f, 0.f};
  f32x4 acc[4][4];
#pragma unroll
  for (int i = 0; i < 4; ++i)
#pragma unroll
    for (int j = 0; j < 4; ++j) acc[i][j] = z4;

  // staging map: per wave-pass, lane i covers LDS bytes [wid*1024 + i*16)
  const int srow = wid * 16 + (lane >> 2);   // 0..63
  const int scol = (lane & 3) * 8;           // 0,8,16,24
  const bf16* Ag = A + (size_t)(bm + srow) * K + scol;
  const bf16* Bg = Bt + (size_t)(bn + srow) * K + scol;
  bf16* Ald = &Al[srow * 32 + scol];
  bf16* Bld = &Bl[srow * 32 + scol];
  const size_t half = (size_t)64 * K;

  for (int k0 = 0; k0 < K; k0 += 32) {
    __syncthreads();
    GL16(Ag + k0, Ald);
    GL16(Ag + k0 + half, Ald + 64 * 32);
    GL16(Bg + k0, Bld);
    GL16(Bg + k0 + half, Bld + 64 * 32);
    __syncthreads();
    bf16x8 af[4], bfr[4];
#pragma unroll
    for (int mi = 0; mi < 4; ++mi)
      af[mi] = *(const bf16x8*)&Al[(wm + mi * 16 + l16) * 32 + g * 8];
#pragma unroll
    for (int ni = 0; ni < 4; ++ni)
      bfr[ni] = *(const bf16x8*)&Bl[(wn + ni * 16 + l16) * 32 + g * 8];
#pragma unroll
    for (int mi = 0; mi < 4; ++mi)
#pragma unroll
      for (int ni = 0; ni < 4; ++ni)
        acc[mi][ni] = mfma16(af[mi], bfr[ni], acc[mi][ni]);
  }

#pragma unroll
  for (int mi = 0; mi < 4; ++mi) {
#pragma unroll
    for (int ni = 0; ni < 4; ++ni) {
#pragma unroll
      for (int r = 0; r < 4; ++r) {
        const int row = bm + wm + mi * 16 + g * 4 + r;
        const int col = bn + wn + ni * 16 + l16;
        float v = acc[mi][ni][r];
        if (BIAS) v += bias[col];
        if (RES)  v += resid[(size_t)row * N + col];
        if (RELU) v = fmaxf(v, 0.f);
        const size_t idx = (size_t)row * N + col;
        if (OUTB) Cb[idx] = (bf16)v;
        else      Cf[idx] = v;
      }
    }
  }
}

// ---------------------------------------------------------------------------
// Flash attention, MFMA. One block = (b, h, 64-row q tile), 4 waves, each
// wave owns 16 q rows. KV tiles of 64. V staged transposed in LDS.
// Q/K/V token-major with row strides qs/kvs; O stride 512. Seqs = 512.
// ---------------------------------------------------------------------------
template<int CAUSAL>
__global__ __launch_bounds__(256, 2) void attn_k(
    const bf16* __restrict__ Q, const bf16* __restrict__ Kg,
    const bf16* __restrict__ Vg, bf16* __restrict__ O, int qs, int kvs)
{
  __shared__ __align__(16) bf16 vt[64 * 64];      // [dh][t]
  __shared__ __align__(16) bf16 pl[4][16 * 64];   // per-wave P [r][t]
  const int tid = threadIdx.x;
  const int wid = tid >> 6, lane = tid & 63;
  const int g = lane >> 4, l16 = lane & 15;
  const int b = blockIdx.z, h = blockIdx.y;
  const int q0 = blockIdx.x * 64 + wid * 16;
  const size_t tokQ = (size_t)b * 512 + q0;

  const bf16* qp = Q + (tokQ + l16) * (size_t)qs + h * 64 + g * 8;
  const bf16x8 qf0 = *(const bf16x8*)qp;
  const bf16x8 qf1 = *(const bf16x8*)(qp + 32);
  const bf16* Kb = Kg + (size_t)b * 512 * kvs + h * 64;
  const bf16* Vb = Vg + (size_t)b * 512 * kvs + h * 64;

  const f32x4 z4 = {0.f, 0.f, 0.f, 0.f};
  float m[4], ls[4];
  f32x4 o[4];
#pragma unroll
  for (int r = 0; r < 4; ++r) { m[r] = -1e30f; ls[r] = 0.f; o[r] = z4; }

  const int ktmax = CAUSAL ? (int)blockIdx.x : 7;
  for (int kt = 0; kt <= ktmax; ++kt) {
    const int t0 = kt * 64;
    __syncthreads();   // prev-iter LDS reads complete before overwrite
    // stage V tile transposed: vt[dh][t]
    for (int u = tid; u < 512; u += 256) {
      const int t = u >> 3, dh0 = (u & 7) * 8;
      const bf16x8 vv = *(const bf16x8*)(Vb + (size_t)(t0 + t) * kvs + dh0);
#pragma unroll
      for (int e = 0; e < 8; ++e) vt[(dh0 + e) * 64 + t] = vv[e];
    }
    // QK^T -> 4 16x16 tiles per wave (t cols t0 + jt*16 + l16)
    f32x4 sc[4];
#pragma unroll
    for (int jt = 0; jt < 4; ++jt) sc[jt] = z4;
#pragma unroll
    for (int jt = 0; jt < 4; ++jt) {
      const bf16* kp = Kb + (size_t)(t0 + jt * 16 + l16) * kvs + g * 8;
      sc[jt] = mfma16(qf0, *(const bf16x8*)kp, sc[jt]);
      sc[jt] = mfma16(qf1, *(const bf16x8*)(kp + 32), sc[jt]);
    }
    // online softmax per row r (row = g*4+r, col = jt*16+l16)
#pragma unroll
    for (int r = 0; r < 4; ++r) {
      const int srow = q0 + g * 4 + r;
      float pv[4];
      float mx = -1e30f;
#pragma unroll
      for (int jt = 0; jt < 4; ++jt) {
        float v = sc[jt][r] * 0.125f;   // 1/sqrt(64)
        if (CAUSAL && (t0 + jt * 16 + l16) > srow) v = -1e30f;
        pv[jt] = v;
        mx = fmaxf(mx, v);
      }
#pragma unroll
      for (int msk = 8; msk; msk >>= 1) mx = fmaxf(mx, __shfl_xor(mx, msk));
      const float mn = fmaxf(m[r], mx);
      const float corr = __expf(m[r] - mn);
      float s = 0.f;
#pragma unroll
      for (int jt = 0; jt < 4; ++jt) {
        const float p = __expf(pv[jt] - mn);
        s += p;
        pl[wid][(g * 4 + r) * 64 + jt * 16 + l16] = (bf16)p;
      }
#pragma unroll
      for (int msk = 8; msk; msk >>= 1) s += __shfl_xor(s, msk);
      ls[r] = ls[r] * corr + s;
      m[r] = mn;
#pragma unroll
      for (int j = 0; j < 4; ++j) o[j][r] *= corr;
    }
    __syncthreads();   // V staged + P visible
    const bf16x8 pa0 = *(const bf16x8*)&pl[wid][l16 * 64 + g * 8];
    const bf16x8 pa1 = *(const bf16x8*)&pl[wid][l16 * 64 + 32 + g * 8];
#pragma unroll
    for (int j = 0; j < 4; ++j) {
      const bf16x8 vf0 = *(const bf16x8*)&vt[(j * 16 + l16) * 64 + g * 8];
      const bf16x8 vf1 = *(const bf16x8*)&vt[(j * 16 + l16) * 64 + 32 + g * 8];
      o[j] = mfma16(pa0, vf0, o[j]);
      o[j] = mfma16(pa1, vf1, o[j]);
    }
  }
#pragma unroll
  for (int r = 0; r < 4; ++r) {
    const float inv = 1.f / ls[r];
    bf16* op = O + (tokQ + g * 4 + r) * 512 + h * 64;
#pragma unroll
    for (int j = 0; j < 4; ++j) op[j * 16 + l16] = (bf16)(o[j][r] * inv);
  }
}

// ---------------------------------------------------------------------------
// LayerNorm over D=512. One wave per row; writes fp32 and (optional) bf16.
// ---------------------------------------------------------------------------
__global__ __launch_bounds__(256) void ln_k(
    const float* __restrict__ z, const float* __restrict__ gam,
    const float* __restrict__ bet, float* __restrict__ of,
    bf16* __restrict__ ob)
{
  const int wid = threadIdx.x >> 6, lane = threadIdx.x & 63;
  const int row = blockIdx.x * 4 + wid;
  const f32x4* zr = (const f32x4*)(z + (size_t)row * 512);
  const f32x4 a = zr[lane], c = zr[lane + 64];
  float s = 0.f, ss = 0.f;
#pragma unroll
  for (int e = 0; e < 4; ++e) {
    s += a[e] + c[e];
    ss += a[e] * a[e] + c[e] * c[e];
  }
#pragma unroll
  for (int msk = 32; msk; msk >>= 1) {
    s += __shfl_xor(s, msk);
    ss += __shfl_xor(ss, msk);
  }
  const float mean = s * (1.f / 512.f);
  const float var = ss * (1.f / 512.f) - mean * mean;
  const float rstd = rsqrtf(var + 1e-5f);
  const f32x4* gp = (const f32x4*)gam;
  const f32x4* bp = (const f32x4*)bet;
  const f32x4 g0 = gp[lane], g1 = gp[lane + 64];
  const f32x4 b0 = bp[lane], b1 = bp[lane + 64];
  f32x4 o0, o1;
#pragma unroll
  for (int e = 0; e < 4; ++e) {
    o0[e] = (a[e] - mean) * rstd * g0[e] + b0[e];
    o1[e] = (c[e] - mean) * rstd * g1[e] + b1[e];
  }
  f32x4* ofr = (f32x4*)(of + (size_t)row * 512);
  ofr[lane] = o0;
  ofr[lane + 64] = o1;
  if (ob) {
    bf16x4 c0, c1;
#pragma unroll
    for (int e = 0; e < 4; ++e) { c0[e] = (bf16)o0[e]; c1[e] = (bf16)o1[e]; }
    bf16x4* obr = (bf16x4*)(ob + (size_t)row * 512);
    obr[lane] = c0;
    obr[lane + 64] = c1;
  }
}

// ---------------------------------------------------------------------------
// Tiled transpose + fp32->bf16 cast: per batch z, src [R][C] -> dst [C][R].
// dst block offset = (z/bpl)*lstride + (z%bpl)*R*C + boff.
// ---------------------------------------------------------------------------
__global__ void transpose_cast(const float* __restrict__ src, bf16* __restrict__ dst,
                               int R, int C, int bpl, size_t lstride, size_t boff)
{
  __shared__ float t[32][33];
  const int z = blockIdx.z;
  src += (size_t)z * R * C;
  dst += (size_t)(z / bpl) * lstride + (size_t)(z % bpl) * ((size_t)R * C) + boff;
  const int c0 = blockIdx.x * 32, r0 = blockIdx.y * 32;
  const int tx = threadIdx.x, ty = threadIdx.y;   // (32, 8)
#pragma unroll
  for (int j = 0; j < 32; j += 8)
    t[ty + j][tx] = src[(size_t)(r0 + ty + j) * C + c0 + tx];
  __syncthreads();
#pragma unroll
  for (int j = 0; j < 32; j += 8)
    dst[(size_t)(c0 + ty + j) * R + r0 + tx] = (bf16)t[tx][ty + j];
}

__global__ void cast4(const float* __restrict__ s, bf16* __restrict__ d)
{
  const int i = blockIdx.x * 256 + threadIdx.x;
  const f32x4 v = ((const f32x4*)s)[i];
  bf16x4 c;
#pragma unroll
  for (int e = 0; e < 4; ++e) c[e] = (bf16)v[e];
  ((bf16x4*)d)[i] = c;
}

// ---------------------------------------------------------------------------
extern "C" void kernel_launch(void* const* d_in, const int* in_sizes, int n_in,
                              void* d_out, int out_size, void* d_ws, size_t ws_size,
                              hipStream_t stream)
{
  (void)in_sizes; (void)n_in; (void)out_size; (void)ws_size;
  const float* x   = (const float*)d_in[0];
  const float* y   = (const float*)d_in[1];
  const float* Wq1 = (const float*)d_in[2];
  const float* Wk1 = (const float*)d_in[3];
  const float* Wv1 = (const float*)d_in[4];
  const float* Wo1 = (const float*)d_in[5];
  const float* Wq2 = (const float*)d_in[6];
  const float* Wk2 = (const float*)d_in[7];
  const float* Wv2 = (const float*)d_in[8];
  const float* Wo2 = (const float*)d_in[9];
  const float* W1  = (const float*)d_in[10];
  const float* b1  = (const float*)d_in[11];
  const float* W2  = (const float*)d_in[12];
  const float* b2  = (const float*)d_in[13];
  const float* ln1g = (const float*)d_in[14];
  const float* ln1b = (const float*)d_in[15];
  const float* ln2g = (const float*)d_in[16];
  const float* ln2b = (const float*)d_in[17];
  const float* ln3g = (const float*)d_in[18];
  const float* ln3b = (const float*)d_in[19];

  char* ws = (char*)d_ws;
  size_t off = 0;
  auto alloc = [&](size_t bytes) -> void* {
    void* p = (void*)(ws + off);
    off += (bytes + 255) & ~(size_t)255;
    return p;
  };

  // weights (bf16, [N][K] transposed)
  bf16* wqkv1t = (bf16*)alloc((size_t)6 * 1536 * 512 * 2);
  bf16* wo1t   = (bf16*)alloc((size_t)6 * 512 * 512 * 2);
  bf16* wq2t   = (bf16*)alloc((size_t)6 * 512 * 512 * 2);
  bf16* wkv2t  = (bf16*)alloc((size_t)6 * 1024 * 512 * 2);
  bf16* wo2t   = (bf16*)alloc((size_t)6 * 512 * 512 * 2);
  bf16* w1t    = (bf16*)alloc((size_t)6 * 512 * 2048 * 2);
  bf16* w2t    = (bf16*)alloc((size_t)6 * 2048 * 512 * 2);
  // activations
  bf16* xb   = (bf16*)alloc((size_t)8192 * 512 * 2);
  bf16* yb   = (bf16*)alloc((size_t)8192 * 512 * 2);
  bf16* qkvb = (bf16*)alloc((size_t)8192 * 1536 * 2);
  bf16* qb   = (bf16*)alloc((size_t)8192 * 512 * 2);   // contiguous after qkvb
  bf16* kvb  = (bf16*)alloc((size_t)8192 * 1024 * 2);
  bf16* ab   = (bf16*)alloc((size_t)8192 * 512 * 2);
  bf16* h1b  = (bf16*)alloc((size_t)8192 * 512 * 2);
  bf16* h2b  = (bf16*)alloc((size_t)8192 * 512 * 2);
  float* zf  = (float*)alloc((size_t)8192 * 512 * 4);
  float* h1f = (float*)alloc((size_t)8192 * 512 * 4);
  float* h2f = (float*)alloc((size_t)8192 * 512 * 4);
  float* xf  = (float*)alloc((size_t)8192 * 512 * 4);
  bf16* f1b  = qkvb;   // aliases qkvb+qb (33.5 MB), both dead during FFN

  // --- weight prep ---
  const dim3 tb(32, 8);
  transpose_cast<<<dim3(2, 16, 48), tb, 0, stream>>>(Wq1, wqkv1t, 512, 64, 8, (size_t)1536 * 512, 0);
  transpose_cast<<<dim3(2, 16, 48), tb, 0, stream>>>(Wk1, wqkv1t, 512, 64, 8, (size_t)1536 * 512, (size_t)512 * 512);
  transpose_cast<<<dim3(2, 16, 48), tb, 0, stream>>>(Wv1, wqkv1t, 512, 64, 8, (size_t)1536 * 512, (size_t)1024 * 512);
  transpose_cast<<<dim3(16, 16, 6), tb, 0, stream>>>(Wo1, wo1t, 512, 512, 1, (size_t)512 * 512, 0);
  transpose_cast<<<dim3(2, 16, 48), tb, 0, stream>>>(Wq2, wq2t, 512, 64, 8, (size_t)512 * 512, 0);
  transpose_cast<<<dim3(2, 16, 48), tb, 0, stream>>>(Wk2, wkv2t, 512, 64, 8, (size_t)1024 * 512, 0);
  transpose_cast<<<dim3(2, 16, 48), tb, 0, stream>>>(Wv2, wkv2t, 512, 64, 8, (size_t)1024 * 512, (size_t)512 * 512);
  transpose_cast<<<dim3(16, 16, 6), tb, 0, stream>>>(Wo2, wo2t, 512, 512, 1, (size_t)512 * 512, 0);
  transpose_cast<<<dim3(64, 16, 6), tb, 0, stream>>>(W1, w1t, 512, 2048, 1, (size_t)512 * 2048, 0);
  transpose_cast<<<dim3(16, 64, 6), tb, 0, stream>>>(W2, w2t, 2048, 512, 1, (size_t)2048 * 512, 0);
  cast4<<<4096, 256, 0, stream>>>(x, xb);
  cast4<<<4096, 256, 0, stream>>>(y, yb);

  const float* curx = x;
  const bf16* curxb = xb;
  const dim3 g512(4, 64), g1024(8, 64), g1536(12, 64), gff(16, 64);

  for (int l = 0; l < 6; ++l) {
    const bf16* WQKV1 = wqkv1t + (size_t)l * 1536 * 512;
    const bf16* WO1   = wo1t   + (size_t)l * 512 * 512;
    const bf16* WQ2   = wq2t   + (size_t)l * 512 * 512;
    const bf16* WKV2  = wkv2t  + (size_t)l * 1024 * 512;
    const bf16* WO2   = wo2t   + (size_t)l * 512 * 512;
    const bf16* W1T   = w1t    + (size_t)l * 2048 * 512;
    const bf16* W2T   = w2t    + (size_t)l * 512 * 2048;

    // masked self-attention + residual + LN1
    gemm_k<0, 0, 0, 1><<<g1536, 256, 0, stream>>>(curxb, WQKV1, nullptr, qkvb,
                                                  nullptr, nullptr, 8192, 1536, 512);
    attn_k<1><<<dim3(8, 8, 16), 256, 0, stream>>>(qkvb, qkvb + 512, qkvb + 1024, ab, 1536, 1536);
    gemm_k<0, 0, 1, 0><<<g512, 256, 0, stream>>>(ab, WO1, zf, nullptr,
                                                 nullptr, curx, 8192, 512, 512);
    ln_k<<<2048, 256, 0, stream>>>(zf, ln1g + l * 512, ln1b + l * 512, h1f, h1b);

    // cross-attention + residual + LN2
    gemm_k<0, 0, 0, 1><<<g512, 256, 0, stream>>>(h1b, WQ2, nullptr, qb,
                                                 nullptr, nullptr, 8192, 512, 512);
    gemm_k<0, 0, 0, 1><<<g1024, 256, 0, stream>>>(yb, WKV2, nullptr, kvb,
                                                  nullptr, nullptr, 8192, 1024, 512);
    attn_k<0><<<dim3(8, 8, 16), 256, 0, stream>>>(qb, kvb, kvb + 512, ab, 512, 1024);
    gemm_k<0, 0, 1, 0><<<g512, 256, 0, stream>>>(ab, WO2, zf, nullptr,
                                                 nullptr, h1f, 8192, 512, 512);
    ln_k<<<2048, 256, 0, stream>>>(zf, ln2g + l * 512, ln2b + l * 512, h2f, h2b);

    // FFN + residual + LN3
    gemm_k<1, 1, 0, 1><<<gff, 256, 0, stream>>>(h2b, W1T, nullptr, f1b,
                                                b1 + l * 2048, nullptr, 8192, 2048, 512);
    gemm_k<0, 1, 1, 0><<<g512, 256, 0, stream>>>(f1b, W2T, zf, nullptr,
                                                 b2 + l * 512, h2f, 8192, 512, 2048);
    float* outf = (l == 5) ? (float*)d_out : xf;
    bf16* outb  = (l == 5) ? nullptr : xb;
    ln_k<<<2048, 256, 0, stream>>>(zf, ln3g + l * 512, ln3b + l * 512, outf, outb);
    curx = xf;
    curxb = xb;
  }
}